// Round 7
// baseline (214.104 us; speedup 1.0000x reference)
//
#include <hip/hip_runtime.h>
#include <hip/hip_bf16.h>
#include <stdint.h>

#define Bdim 8
#define Nseq 1024
#define Cdim 768
#define Hn 12
#define HD 64
#define EPSf 1e-6f

typedef __bf16 bf16;
typedef __bf16 bf16x8 __attribute__((ext_vector_type(8)));
typedef float f32x4 __attribute__((ext_vector_type(4)));

static __device__ __forceinline__ void gload_lds16(const bf16* g, bf16* lds) {
  __builtin_amdgcn_global_load_lds(
      (const __attribute__((address_space(1))) uint32_t*)g,
      (__attribute__((address_space(3))) uint32_t*)lds, 16, 0, 0);
}

// ---------------- fused fp32 -> bf16 convert for x, Wqkv, Wproj; also zeroes CS
#define NX (Bdim * Nseq * Cdim)
#define NWQ (3 * Cdim * Cdim)
#define NWP (Cdim * Cdim)
__global__ __launch_bounds__(256) void cvt_all(
    const float* __restrict__ x, const float* __restrict__ wq, const float* __restrict__ wp,
    bf16* __restrict__ Xb, bf16* __restrict__ Wqb, bf16* __restrict__ Wpb,
    float* __restrict__ CS) {
  if (blockIdx.x < 24) CS[blockIdx.x * 256 + threadIdx.x] = 0.f;  // 96*64 floats
  const int i = (blockIdx.x * 256 + threadIdx.x) * 8;
  const float* src;
  bf16* dst;
  int off;
  if (i < NX) { src = x; dst = Xb; off = i; }
  else if (i < NX + NWQ) { src = wq; dst = Wqb; off = i - NX; }
  else { src = wp; dst = Wpb; off = i - NX - NWQ; }
  float4 a = *(const float4*)(src + off);
  float4 b = *(const float4*)(src + off + 4);
  bf16x8 o;
  o[0] = (bf16)a.x; o[1] = (bf16)a.y; o[2] = (bf16)a.z; o[3] = (bf16)a.w;
  o[4] = (bf16)b.x; o[5] = (bf16)b.y; o[6] = (bf16)b.z; o[7] = (bf16)b.w;
  *(bf16x8*)(dst + off) = o;
}

// ---------------- QKV GEMM: 128x128 tile, BK=32, m97 layout, double-buffered staging
// XCD-striped; Vt stored KEY-INTERLEAVED (pos32 = quad*8 + g16*4 + r); fused V colsum.
__global__ __launch_bounds__(256) void gemm_qkv(
    const bf16* __restrict__ X, const bf16* __restrict__ W,
    bf16* __restrict__ Qb, bf16* __restrict__ Kb, bf16* __restrict__ Vt,
    float* __restrict__ CS) {
  __shared__ __align__(16) bf16 As[2][128 * 32];
  __shared__ __align__(16) bf16 Bs[2][128 * 32];
  const int t = threadIdx.x;
  const int lane = t & 63;
  const int w = t >> 6;
  const int l15 = lane & 15, quad = lane >> 4;
  const int wm = w & 1, wn = w >> 1;
  constexpr int K = Cdim;

  const int flat = blockIdx.y * 18 + blockIdx.x;  // grid (18, 64)
  const int xcd = flat & 7, idx = flat >> 3;
  const int my = (idx & 7) + xcd * 8;
  const int nx = idx >> 3;
  const int mbase = my * 128;
  const int nbase = nx * 128;

  // m97-exact staging: chunk ci = j*256+t -> row = ci>>2 (0..127), col = (ci&3)*8
  const int r0 = t >> 2, c0 = (t & 3) * 8;
  const bf16* Ag = X + (size_t)(mbase + r0) * K + c0;
  const bf16* Bg = W + (size_t)(nbase + r0) * K + c0;

  f32x4 acc[4][4] = {};

  // prologue: stage tile 0 into buffer 0
  gload_lds16(Ag, &As[0][t * 8]);
  gload_lds16(Ag + (size_t)64 * K, &As[0][2048 + t * 8]);
  gload_lds16(Bg, &Bs[0][t * 8]);
  gload_lds16(Bg + (size_t)64 * K, &Bs[0][2048 + t * 8]);

  for (int kt = 0; kt < K; kt += 32) {
    const int buf = (kt >> 5) & 1;
    __syncthreads();  // drains tile-t staging (in flight for a full compute phase)
    if (kt + 32 < K) {
      const int nb = buf ^ 1;
      gload_lds16(Ag + kt + 32, &As[nb][t * 8]);
      gload_lds16(Ag + (size_t)64 * K + kt + 32, &As[nb][2048 + t * 8]);
      gload_lds16(Bg + kt + 32, &Bs[nb][t * 8]);
      gload_lds16(Bg + (size_t)64 * K + kt + 32, &Bs[nb][2048 + t * 8]);
    }
    bf16x8 a[4], b[4];
#pragma unroll
    for (int mt = 0; mt < 4; mt++)
      a[mt] = *(const bf16x8*)(&As[buf][(wm * 64 + mt * 16 + l15) * 32 + quad * 8]);
#pragma unroll
    for (int nt = 0; nt < 4; nt++)
      b[nt] = *(const bf16x8*)(&Bs[buf][(wn * 64 + nt * 16 + l15) * 32 + quad * 8]);
#pragma unroll
    for (int mt = 0; mt < 4; mt++)
#pragma unroll
      for (int nt = 0; nt < 4; nt++)
        acc[mt][nt] = __builtin_amdgcn_mfma_f32_16x16x32_bf16(a[mt], b[nt], acc[mt][nt], 0, 0, 0);
  }

  const int s = nbase / Cdim;
  const float oscale = (s == 0) ? 0.125f : 1.0f;
  const int jbase = (nbase % Cdim) + wn * 64;
  const int b0 = mbase >> 10;
#pragma unroll
  for (int nt = 0; nt < 4; nt++) {
    const int jj = jbase + nt * 16 + l15;
    const int h = jj >> 6, d = jj & 63;
#pragma unroll
    for (int mt = 0; mt < 4; mt++) {
#pragma unroll
      for (int r = 0; r < 4; r++) {
        const int m = mbase + wm * 64 + mt * 16 + quad * 4 + r;
        const int n = m & 1023;
        const bf16 v = (bf16)(acc[mt][nt][r] * oscale);
        const size_t bh = (size_t)b0 * Hn + h;
        if (s == 0)      Qb[(bh * Nseq + n) * HD + d] = v;
        else if (s == 1) Kb[(bh * Nseq + n) * HD + d] = v;
        else {
          const int nperm = (n & ~31) | (quad * 8 + (mt & 1) * 4 + r);
          Vt[(bh * HD + d) * Nseq + nperm] = v;
        }
      }
    }
  }
  if (s == 2) {  // fused V column-sum partials (permutation-invariant)
#pragma unroll
    for (int nt = 0; nt < 4; nt++) {
      float v = 0.f;
#pragma unroll
      for (int mt = 0; mt < 4; mt++)
#pragma unroll
        for (int r = 0; r < 4; r++) v += acc[mt][nt][r];
      v += __shfl_xor(v, 16);
      v += __shfl_xor(v, 32);
      if (quad == 0) {
        const int jj = jbase + nt * 16 + l15;
        atomicAdd(&CS[((size_t)b0 * Hn + (jj >> 6)) * HD + (jj & 63)], v);
      }
    }
  }
}

// ---------------- deferred-max softmax update on S^T tiles
template <bool DIAG>
static __device__ __forceinline__ void smax_update(
    f32x4 (&S)[2][4], float (&mx)[2], float (&lrow)[2],
    const float (&polq)[2], const float4 (&pk)[4],
    int kt, int qbase, int quad, int l15) {
#pragma unroll
  for (int u = 0; u < 2; u++) {
    const float pm = polq[u];
    const int q = qbase + u * 16 + l15;
    float m4 = -1e30f, psum = 0.f;
#pragma unroll
    for (int kg = 0; kg < 4; kg++)
#pragma unroll
      for (int r = 0; r < 4; r++) m4 = fmaxf(m4, S[u][kg][r]);
    mx[u] = fmaxf(mx[u], m4);
#pragma unroll
    for (int kg = 0; kg < 4; kg++) {
      const float* pkk = (const float*)&pk[kg];
#pragma unroll
      for (int r = 0; r < 4; r++) {
        const float e = __expf(S[u][kg][r]);
        float p = e * (pkk[r] * pm);
        if (DIAG) p = (q == kt + kg * 16 + quad * 4 + r) ? e : p;
        S[u][kg][r] = p;
        psum += p;
      }
    }
    lrow[u] += psum;
  }
}

// ---------------- fused flash attention, S^T form, double-buffered K/V staging
__global__ __launch_bounds__(256) void attn_fused(
    const bf16* __restrict__ Qb, const bf16* __restrict__ Kb, const bf16* __restrict__ Vt,
    const float* __restrict__ pol, const float* __restrict__ CS, bf16* __restrict__ O) {
  __shared__ __align__(16) bf16 Ks[2][64 * 64];
  __shared__ __align__(16) bf16 Vs[2][64 * 64];
  __shared__ float Ps[Nseq];
  const int t = threadIdx.x, w = t >> 6, lane = t & 63;
  const int l15 = lane & 15, quad = lane >> 4;

  const int bx = blockIdx.x;
  const int g = (bx & 7) + 8 * (bx >> 6);  // head 0..95 -> XCD g%8
  const int qt = (bx >> 3) & 7;
  const int b_ = g / Hn, h = g % Hn;
  const int qbase = qt * 128 + w * 32;
  const int ktdiag = qbase & ~63;

  const bf16* Qp = Qb + (size_t)g * Nseq * HD;
  const bf16* Kp = Kb + (size_t)g * Nseq * HD;
  const bf16* Vp = Vt + (size_t)g * HD * Nseq;
  const float* polb = pol + (size_t)b_ * Nseq;

  *(float4*)(Ps + t * 4) = *(const float4*)(polb + t * 4);

  const int ci0 = t, ci1 = t + 256;
  const int row0 = ci0 >> 3, seg0 = (ci0 & 7) ^ (row0 & 7);
  const int row1 = ci1 >> 3, seg1 = (ci1 & 7) ^ (row1 & 7);

  // Q fragments (used as B-operand): B[n=query=l15][k=d=quad*8+j]
  bf16x8 aq[2][2];
#pragma unroll
  for (int u = 0; u < 2; u++) {
    aq[u][0] = *(const bf16x8*)(Qp + (qbase + u * 16 + l15) * HD + quad * 8);
    aq[u][1] = *(const bf16x8*)(Qp + (qbase + u * 16 + l15) * HD + 32 + quad * 8);
  }
  float polq[2] = { polb[qbase + l15], polb[qbase + 16 + l15] };

  float mx[2] = { -1e30f, -1e30f }, lrow[2] = { 0.f, 0.f };
  f32x4 oacc[2][4] = {};

  // prologue: stage tile 0 into buffer 0
  gload_lds16(Kp + row0 * HD + seg0 * 8, &Ks[0][ci0 * 8]);
  gload_lds16(Kp + row1 * HD + seg1 * 8, &Ks[0][ci1 * 8]);
  gload_lds16(Vp + (size_t)row0 * Nseq + seg0 * 8, &Vs[0][ci0 * 8]);
  gload_lds16(Vp + (size_t)row1 * Nseq + seg1 * 8, &Vs[0][ci1 * 8]);

  for (int kt = 0; kt < Nseq; kt += 64) {
    const int buf = (kt >> 6) & 1;
    __syncthreads();
    if (kt + 64 < Nseq) {
      const int nb = buf ^ 1;
      gload_lds16(Kp + (kt + 64 + row0) * HD + seg0 * 8, &Ks[nb][ci0 * 8]);
      gload_lds16(Kp + (kt + 64 + row1) * HD + seg1 * 8, &Ks[nb][ci1 * 8]);
      gload_lds16(Vp + (size_t)row0 * Nseq + kt + 64 + seg0 * 8, &Vs[nb][ci0 * 8]);
      gload_lds16(Vp + (size_t)row1 * Nseq + kt + 64 + seg1 * 8, &Vs[nb][ci1 * 8]);
    }

    // ---- K@Q^T -> S^T: A=K (m=key), B=Q (n=query)
    f32x4 S[2][4] = {};
#pragma unroll
    for (int kg = 0; kg < 4; kg++) {
      const int row = kg * 16 + l15;
      bf16x8 bk0 = *(const bf16x8*)(&Ks[buf][row * 64 + ((quad ^ (row & 7)) * 8)]);
      bf16x8 bk1 = *(const bf16x8*)(&Ks[buf][row * 64 + (((quad ^ 4) ^ (row & 7)) * 8)]);
#pragma unroll
      for (int u = 0; u < 2; u++) {
        S[u][kg] = __builtin_amdgcn_mfma_f32_16x16x32_bf16(bk0, aq[u][0], S[u][kg], 0, 0, 0);
        S[u][kg] = __builtin_amdgcn_mfma_f32_16x16x32_bf16(bk1, aq[u][1], S[u][kg], 0, 0, 0);
      }
    }

    float4 pk[4];
#pragma unroll
    for (int kg = 0; kg < 4; kg++)
      pk[kg] = *(const float4*)(Ps + kt + kg * 16 + quad * 4);

    if (kt == ktdiag)
      smax_update<true>(S, mx, lrow, polq, pk, kt, qbase, quad, l15);
    else
      smax_update<false>(S, mx, lrow, polq, pk, kt, qbase, quad, l15);

    // ---- PV: A=P (lane-natural k-permuted A-layout), B=V (interleaved Vt)
#pragma unroll
    for (int hh = 0; hh < 2; hh++) {
      bf16x8 ap[2];
#pragma unroll
      for (int u = 0; u < 2; u++)
#pragma unroll
        for (int j = 0; j < 4; j++) {
          ap[u][j] = (bf16)S[u][2 * hh][j];
          ap[u][4 + j] = (bf16)S[u][2 * hh + 1][j];
        }
#pragma unroll
      for (int c = 0; c < 4; c++) {
        const int row = c * 16 + l15;
        bf16x8 bv = *(const bf16x8*)(&Vs[buf][row * 64 + (((hh * 4 + quad) ^ (row & 7)) * 8)]);
#pragma unroll
        for (int u = 0; u < 2; u++)
          oacc[u][c] = __builtin_amdgcn_mfma_f32_16x16x32_bf16(ap[u], bv, oacc[u][c], 0, 0, 0);
      }
    }
  }

  // ---- epilogue: reduce l,m across quads (lanes sharing l15), redistribute to rows
  const float epsN = EPSf / (float)Nseq;
  float rden[2][4], eterm[2][4];
#pragma unroll
  for (int u = 0; u < 2; u++) {
    float v = lrow[u];
    v += __shfl_xor(v, 16);
    v += __shfl_xor(v, 32);
    float m = mx[u];
    m = fmaxf(m, __shfl_xor(m, 16));
    m = fmaxf(m, __shfl_xor(m, 32));
    const float em = __expf(m);
    const float den = v + EPSf * em;
    const float eN = epsN * em;
    const int base = lane & 48;
#pragma unroll
    for (int r = 0; r < 4; r++) {
      rden[u][r] = 1.f / __shfl(den, base | (quad * 4 + r));
      eterm[u][r] = __shfl(eN, base | (quad * 4 + r));
    }
  }
  const float* CSp = CS + (size_t)g * HD;
#pragma unroll
  for (int c = 0; c < 4; c++) {
    const float cs = CSp[c * 16 + l15];
#pragma unroll
    for (int u = 0; u < 2; u++)
#pragma unroll
      for (int r = 0; r < 4; r++) {
        const int q = qbase + u * 16 + quad * 4 + r;
        const float val = (oacc[u][c][r] + cs * eterm[u][r]) * rden[u][r];
        O[((size_t)b_ * Nseq + q) * Cdim + h * 64 + c * 16 + l15] = (bf16)val;
      }
  }
}

// ---------------- proj GEMM: 64x128 tile, BK=32, m97 layout, double-buffered
__global__ __launch_bounds__(256) void gemm_proj(
    const bf16* __restrict__ A_, const bf16* __restrict__ W,
    const float* __restrict__ bias, float* __restrict__ out) {
  __shared__ __align__(16) bf16 As[2][64 * 32];
  __shared__ __align__(16) bf16 Bs[2][128 * 32];
  const int t = threadIdx.x;
  const int lane = t & 63;
  const int wn = t >> 6;
  const int l15 = lane & 15, quad = lane >> 4;
  constexpr int K = Cdim;

  const int flat = blockIdx.y * 6 + blockIdx.x;  // grid (6, 128)
  const int xcd = flat & 7, idx = flat >> 3;
  const int my = (idx & 15) + xcd * 16;
  const int nx = idx >> 4;
  const int mbase = my * 64;
  const int nbase = nx * 128;

  const int r0 = t >> 2, c0 = (t & 3) * 8;
  const bf16* Ag = A_ + (size_t)(mbase + r0) * K + c0;
  const bf16* Bg = W + (size_t)(nbase + r0) * K + c0;

  f32x4 acc[4][2] = {};

  // prologue: stage tile 0 into buffer 0
  gload_lds16(Ag, &As[0][t * 8]);
  gload_lds16(Bg, &Bs[0][t * 8]);
  gload_lds16(Bg + (size_t)64 * K, &Bs[0][2048 + t * 8]);

  for (int kt = 0; kt < K; kt += 32) {
    const int buf = (kt >> 5) & 1;
    __syncthreads();
    if (kt + 32 < K) {
      const int nb = buf ^ 1;
      gload_lds16(Ag + kt + 32, &As[nb][t * 8]);
      gload_lds16(Bg + kt + 32, &Bs[nb][t * 8]);
      gload_lds16(Bg + (size_t)64 * K + kt + 32, &Bs[nb][2048 + t * 8]);
    }
    bf16x8 a[4], b[2];
#pragma unroll
    for (int mt = 0; mt < 4; mt++)
      a[mt] = *(const bf16x8*)(&As[buf][(mt * 16 + l15) * 32 + quad * 8]);
#pragma unroll
    for (int nt = 0; nt < 2; nt++)
      b[nt] = *(const bf16x8*)(&Bs[buf][(wn * 32 + nt * 16 + l15) * 32 + quad * 8]);
#pragma unroll
    for (int mt = 0; mt < 4; mt++)
#pragma unroll
      for (int nt = 0; nt < 2; nt++)
        acc[mt][nt] = __builtin_amdgcn_mfma_f32_16x16x32_bf16(a[mt], b[nt], acc[mt][nt], 0, 0, 0);
  }

#pragma unroll
  for (int nt = 0; nt < 2; nt++) {
    const int j = nbase + wn * 32 + nt * 16 + l15;
    const float bj = bias[j];
#pragma unroll
    for (int mt = 0; mt < 4; mt++)
#pragma unroll
      for (int r = 0; r < 4; r++) {
        const int m = mbase + mt * 16 + quad * 4 + r;
        out[(size_t)m * Cdim + j] = acc[mt][nt][r] + bj;
      }
  }
}

extern "C" void kernel_launch(void* const* d_in, const int* in_sizes, int n_in,
                              void* d_out, int out_size, void* d_ws, size_t ws_size,
                              hipStream_t stream) {
  const float* x = (const float*)d_in[0];
  const float* pol = (const float*)d_in[1];
  const float* Wqkv = (const float*)d_in[2];
  const float* Wproj = (const float*)d_in[3];
  const float* bproj = (const float*)d_in[4];
  float* out = (float*)d_out;
  char* ws = (char*)d_ws;

  const size_t SZ = (size_t)Bdim * Hn * Nseq * HD * sizeof(bf16);  // 12.58 MB
  bf16* Qb = (bf16*)(ws);
  bf16* Kb = (bf16*)(ws + SZ);
  bf16* Vt = (bf16*)(ws + 2 * SZ);
  bf16* O  = (bf16*)(ws + 3 * SZ);
  float* CS = (float*)(ws + 4 * SZ);
  bf16* Xb = (bf16*)(ws + 4 * SZ + 32 * 1024);
  bf16* Wqkvb = Xb + (size_t)Bdim * Nseq * Cdim;
  bf16* Wprojb = Wqkvb + (size_t)3 * Cdim * Cdim;

  cvt_all<<<(NX + NWQ + NWP) / 2048, 256, 0, stream>>>(x, Wqkv, Wproj, Xb, Wqkvb, Wprojb, CS);
  gemm_qkv<<<dim3(18, 64), 256, 0, stream>>>(Xb, Wqkvb, Qb, Kb, Vt, CS);
  attn_fused<<<Bdim * Hn * (Nseq / 128), 256, 0, stream>>>(Qb, Kb, Vt, pol, CS, O);
  gemm_proj<<<dim3(6, 128), 256, 0, stream>>>(O, Wprojb, bproj, out);
}